// Round 2
// 200.785 us; speedup vs baseline: 1.0203x; 1.0203x over previous
//
#include <hip/hip_runtime.h>

// Flash attention fwd, bf16 MFMA. B=4,H=16,S=2048,D=64, fp32 in/out.
// d_in[0]=k, d_in[1]=q, d_in[2]=v, d_in[3]=scale, d_in[4]=dropout_p (ignored).
//
// R7 = R6 pipeline, hang-hardened:
//  - Double-buffered LDS (KsA/VsA, KsB/VsB as SEPARATE __shared__ objects so
//    AA can prove global_load_lds DMA writes don't alias the tile being read).
//  - 2-phase schedule, ONE __syncthreads per tile, issued AFTER compute:
//      STAGE(t+1 -> other buf); compute(cur buf); __syncthreads()
//    __syncthreads' implicit vmcnt(0) drain lands after a full tile of
//    compute, so the prefetched loads are already home. No raw s_barrier asm
//    (R6's suspect). kt-loop unrolled x2 so buffer choice is compile-time.
//  - QK^T accumulators seeded from hoisted zero vector.
//  - pk_trunc = single v_perm_b32.
//  - XCD-aware bijective block swizzle (1024 wgs = 8 XCDs x 128): each XCD
//    owns 8 consecutive bh -> its K+V bf16 working set (4 MB) fits one L2.

using short8 = __attribute__((ext_vector_type(8))) short;
using f32x4  = __attribute__((ext_vector_type(4))) float;

constexpr int S_LEN = 2048;
constexpr int Dh    = 64;

// RNE f32->bf16 pair pack (low = a)
__device__ inline unsigned pk_bf16(float a, float b) {
    unsigned ua = __float_as_uint(a), ub = __float_as_uint(b);
    ua += 0x7FFFu + ((ua >> 16) & 1u);
    ub += 0x7FFFu + ((ub >> 16) & 1u);
    return (ua >> 16) | (ub & 0xFFFF0000u);
}
// trunc pack: P only; bias cancels since l uses the same bf16 P.
// (a>>16)|(b&0xFFFF0000) == v_perm_b32(S0=b, S1=a, sel=0x07060302)
__device__ inline unsigned pk_trunc(float a, float b) {
    return __builtin_amdgcn_perm(__float_as_uint(b), __float_as_uint(a), 0x07060302u);
}
__device__ inline unsigned dpp_xor1_u(unsigned v) {   // fallback kernel only
    return (unsigned)__builtin_amdgcn_update_dpp(0, (int)v, 0xB1, 0xF, 0xF, true);
}
__device__ inline f32x4 mfma16(short8 a, short8 b, f32x4 c) {
    return __builtin_amdgcn_mfma_f32_16x16x32_bf16(a, b, c, 0, 0, 0);
}
__device__ inline void glds16(const short* g, short* l) {
    __builtin_amdgcn_global_load_lds(
        (const __attribute__((address_space(1))) void*)g,
        (__attribute__((address_space(3))) void*)l, 16, 0, 0);
}

// ---------------- pre-pass: K->bf16, V->bf16 transposed+permuted ----------
__global__ __launch_bounds__(256)
void prepass(const float* __restrict__ K, const float* __restrict__ V,
             short* __restrict__ Kb, short* __restrict__ VtG)
{
    const int t  = threadIdx.x;
    const int kt = blockIdx.x & 31;
    const int bh = blockIdx.x >> 5;
    const size_t tbase = ((size_t)bh * S_LEN + kt * 64) * Dh;

    // K: straight convert, coalesced. 64x64 tile = 4096 elems = 256 thr x 8 x 2.
    #pragma unroll
    for (int i = 0; i < 2; ++i) {
        const float* ks = K + tbase + 8 * (t + 256 * i);
        const float4 a = *(const float4*)ks;
        const float4 b = *(const float4*)(ks + 4);
        uint4 u;
        u.x = pk_bf16(a.x, a.y); u.y = pk_bf16(a.z, a.w);
        u.z = pk_bf16(b.x, b.y); u.w = pk_bf16(b.z, b.w);
        *(uint4*)(Kb + tbase + 8 * (t + 256 * i)) = u;
    }
    // V: transpose 64x64 tile into [d][pos], pos-permuted, key-pair packed
    const float* vs = V + tbase;
    short* vd = VtG + (size_t)bh * Dh * S_LEN;
    const int p2 = t & 31, dcg = t >> 5;
    const int a_ = p2 >> 4, q_ = (p2 >> 2) & 3, b_ = (p2 >> 1) & 1, r0 = (p2 & 1) * 2;
    const int key0 = 32 * a_ + 16 * b_ + 4 * q_ + r0;   // pos 2*p2 <-> key0, 2*p2+1 <-> key0+1
    #pragma unroll
    for (int rr = 0; rr < 2; ++rr) {
        const int dc = dcg + 8 * rr;
        const float4 v0 = *(const float4*)(vs + key0 * Dh + dc * 4);
        const float4 v1 = *(const float4*)(vs + (key0 + 1) * Dh + dc * 4);
        *(unsigned*)&vd[(dc * 4 + 0) * S_LEN + kt * 64 + 2 * p2] = pk_bf16(v0.x, v1.x);
        *(unsigned*)&vd[(dc * 4 + 1) * S_LEN + kt * 64 + 2 * p2] = pk_bf16(v0.y, v1.y);
        *(unsigned*)&vd[(dc * 4 + 2) * S_LEN + kt * 64 + 2 * p2] = pk_bf16(v0.z, v1.z);
        *(unsigned*)&vd[(dc * 4 + 3) * S_LEN + kt * 64 + 2 * p2] = pk_bf16(v0.w, v1.w);
    }
}

// ---------------- main kernel --------------------------------------------
__global__ __launch_bounds__(256, 4)
void fattn_mfma3(const short* __restrict__ Kb, const short* __restrict__ VtG,
                 const float* __restrict__ Qg_, const float* __restrict__ scale_p,
                 float* __restrict__ Og_)
{
    // Separate objects per buffer: lets AA prove DMA-write vs ds_read no-alias.
    __shared__ __align__(16) short KsA[64 * 64];
    __shared__ __align__(16) short VsA[64 * 64];
    __shared__ __align__(16) short KsB[64 * 64];
    __shared__ __align__(16) short VsB[64 * 64];

    const int t    = threadIdx.x;
    const int w    = t >> 6;
    const int lane = t & 63;
    const int cl   = lane & 15;
    const int quad = lane >> 4;

    // XCD-aware bijective swizzle: nwg=1024 = 8 XCDs x 128. XCD k gets
    // logical wgs [128k,128k+128) = 8 full bh's -> K+V bf16 (4 MB) fits its L2.
    const int bid = blockIdx.x;
    const int swz = ((bid & 7) << 7) | (bid >> 3);
    const int qt = swz & 15;
    const int bh = swz >> 4;

    const float qs = (*scale_p) * 1.44269504088896f;   // p = exp2(s)

    const float* Qg = Qg_ + ((size_t)bh * S_LEN + qt * 128) * Dh;
    float*       Og = Og_ + ((size_t)bh * S_LEN + qt * 128) * Dh;

    // ---- Q B-frags (lane n=qrow holds d=quad*8+j+32kk), scale folded ----
    short8 qa[2][2];
    #pragma unroll
    for (int ntq = 0; ntq < 2; ++ntq)
        #pragma unroll
        for (int kk = 0; kk < 2; ++kk) {
            const float* qp = Qg + (w * 32 + ntq * 16 + cl) * Dh + kk * 32 + quad * 8;
            float4 a = *(const float4*)qp;
            float4 b = *(const float4*)(qp + 4);
            union { short8 s; unsigned u[4]; } uu;
            uu.u[0] = pk_bf16(a.x * qs, a.y * qs);
            uu.u[1] = pk_bf16(a.z * qs, a.w * qs);
            uu.u[2] = pk_bf16(b.x * qs, b.y * qs);
            uu.u[3] = pk_bf16(b.z * qs, b.w * qs);
            qa[ntq][kk] = uu.s;
        }

    // ---- staging source pointers (swizzle via global source permutation) ----
    const int rsub = lane >> 3;              // row-in-8 within one glds instr
    const int csw  = (lane & 7) ^ rsub;      // permuted source chunk
    const short* kbase = Kb  + (size_t)bh * S_LEN * Dh + (16 * w + rsub) * Dh   + csw * 8;
    const short* vbase = VtG + (size_t)bh * Dh * S_LEN + (16 * w + rsub) * S_LEN + csw * 8;
    short* ldK0A = &KsA[(16 * w + 0) * 64];
    short* ldK1A = &KsA[(16 * w + 8) * 64];
    short* ldV0A = &VsA[(16 * w + 0) * 64];
    short* ldV1A = &VsA[(16 * w + 8) * 64];
    short* ldK0B = &KsB[(16 * w + 0) * 64];
    short* ldK1B = &KsB[(16 * w + 8) * 64];
    short* ldV0B = &VsB[(16 * w + 0) * 64];
    short* ldV1B = &VsB[(16 * w + 8) * 64];

    // ---- frag LDS byte offsets (row m=16x+cl, chunk quad+4kk, XOR swizzle) ----
    int off[4][2];
    #pragma unroll
    for (int x = 0; x < 4; ++x)
        #pragma unroll
        for (int kk = 0; kk < 2; ++kk)
            off[x][kk] = (((16 * x + cl) * 8 + ((quad + 4 * kk) ^ (cl & 7))) << 4);

    short8 ones;
    #pragma unroll
    for (int i = 0; i < 8; ++i) ones[i] = (short)0x3F80;

    f32x4 o[2][4];
    #pragma unroll
    for (int ntq = 0; ntq < 2; ++ntq)
        #pragma unroll
        for (int nt = 0; nt < 4; ++nt) o[ntq][nt] = (f32x4){0.f, 0.f, 0.f, 0.f};
    f32x4 l_acc[2];
    l_acc[0] = (f32x4){0.f, 0.f, 0.f, 0.f};
    l_acc[1] = (f32x4){0.f, 0.f, 0.f, 0.f};

    const f32x4 z4 = (f32x4){0.f, 0.f, 0.f, 0.f};   // shared C-operand seed

    auto compute_tile = [&](const short* KsT, const short* VsT) {
        // ---- S^T = K Q^T : lane holds col=qrow, rows=keys ----
        f32x4 s[4][2];
        #pragma unroll
        for (int mt = 0; mt < 4; ++mt) {
            const short8 kf0 = *(const short8*)((const char*)KsT + off[mt][0]);
            const short8 kf1 = *(const short8*)((const char*)KsT + off[mt][1]);
            s[mt][0] = mfma16(kf1, qa[0][1], mfma16(kf0, qa[0][0], z4));
            s[mt][1] = mfma16(kf1, qa[1][1], mfma16(kf0, qa[1][0], z4));
        }

        // ---- P = exp2(S^T), pack directly into PV A-frags (registers only)
        // key = 16mt + 4quad + r  ->  pos = 32*(mt>>1) + 8*quad + 4*(mt&1) + r
        short8 pa[2][2];
        #pragma unroll
        for (int ntq = 0; ntq < 2; ++ntq) {
            float e[4][4];
            #pragma unroll
            for (int mt = 0; mt < 4; ++mt)
                #pragma unroll
                for (int r = 0; r < 4; ++r)
                    e[mt][r] = __builtin_amdgcn_exp2f(s[mt][ntq][r]);
            #pragma unroll
            for (int kk = 0; kk < 2; ++kk) {
                union { short8 s8; unsigned u[4]; } uu;
                uu.u[0] = pk_trunc(e[2 * kk][0],     e[2 * kk][1]);
                uu.u[1] = pk_trunc(e[2 * kk][2],     e[2 * kk][3]);
                uu.u[2] = pk_trunc(e[2 * kk + 1][0], e[2 * kk + 1][1]);
                uu.u[3] = pk_trunc(e[2 * kk + 1][2], e[2 * kk + 1][3]);
                pa[ntq][kk] = uu.s8;
            }
        }

        // ---- l += P @ ones ----
        #pragma unroll
        for (int ntq = 0; ntq < 2; ++ntq) {
            l_acc[ntq] = mfma16(pa[ntq][0], ones, l_acc[ntq]);
            l_acc[ntq] = mfma16(pa[ntq][1], ones, l_acc[ntq]);
        }

        // ---- O += P V ----
        #pragma unroll
        for (int nt = 0; nt < 4; ++nt) {
            const short8 vf0 = *(const short8*)((const char*)VsT + off[nt][0]);
            const short8 vf1 = *(const short8*)((const char*)VsT + off[nt][1]);
            o[0][nt] = mfma16(pa[0][1], vf1, mfma16(pa[0][0], vf0, o[0][nt]));
            o[1][nt] = mfma16(pa[1][1], vf1, mfma16(pa[1][0], vf0, o[1][nt]));
        }
    };

#define STAGE(KT, K0, K1, V0, V1) do {                      \
        glds16(kbase + (KT) * 4096,              (K0));     \
        glds16(kbase + (KT) * 4096 + 512,        (K1));     \
        glds16(vbase + (KT) * 64,                (V0));     \
        glds16(vbase + (KT) * 64 + 8 * S_LEN,    (V1));     \
    } while (0)

    // prologue: tile 0 -> buffer A; __syncthreads drains vmcnt
    STAGE(0, ldK0A, ldK1A, ldV0A, ldV1A);
    __syncthreads();

    for (int kt = 0; kt < S_LEN / 64; kt += 2) {
        // even tile: prefetch kt+1 -> B, compute A; barrier drain is cheap
        // because the B-loads had the whole compute phase to land.
        STAGE(kt + 1, ldK0B, ldK1B, ldV0B, ldV1B);
        compute_tile(KsA, VsA);
        __syncthreads();

        // odd tile: prefetch kt+2 -> A (if any), compute B
        if (kt + 2 < S_LEN / 64)
            STAGE(kt + 2, ldK0A, ldK1A, ldV0A, ldV1A);
        compute_tile(KsB, VsB);
        __syncthreads();
    }
#undef STAGE

    // ---- epilogue ----
    #pragma unroll
    for (int ntq = 0; ntq < 2; ++ntq) {
        float inv[4];
        #pragma unroll
        for (int r = 0; r < 4; ++r) inv[r] = 1.0f / l_acc[ntq][r];
        #pragma unroll
        for (int nt = 0; nt < 4; ++nt)
            #pragma unroll
            for (int r = 0; r < 4; ++r)
                Og[(w * 32 + ntq * 16 + quad * 4 + r) * Dh + cl + 16 * nt] =
                    o[ntq][nt][r] * inv[r];
    }
}

// ---------------- fallback (R3, proven): used only if ws too small --------
constexpr int LDS_LD = 72;
__global__ __launch_bounds__(256, 4)
void fattn_mfma2(const float* __restrict__ Kg_, const float* __restrict__ Qg_,
                 const float* __restrict__ Vg_, const float* __restrict__ scale_p,
                 float* __restrict__ Og_)
{
    __shared__ __align__(16) short Ks[64 * LDS_LD];
    __shared__ __align__(16) short Vt[Dh * LDS_LD];
    __shared__ __align__(16) short Ps[4 * 32 * LDS_LD];

    const int t = threadIdx.x, w = t >> 6, lane = t & 63;
    const int c = lane & 15, quad = lane >> 4;
    const int qt = blockIdx.x & 15, bh = blockIdx.x >> 4;
    const float qs = (*scale_p) * 1.44269504088896f;

    const float* Qg = Qg_ + ((size_t)bh * S_LEN + (size_t)qt * 128) * Dh;
    const float* Kg = Kg_ + (size_t)bh * S_LEN * Dh;
    const float* Vg = Vg_ + (size_t)bh * S_LEN * Dh;
    float*       Og = Og_ + ((size_t)bh * S_LEN + (size_t)qt * 128) * Dh;
    const int wPoff = w * 32 * LDS_LD;

    short8 qa[2][2];
    #pragma unroll
    for (int mt = 0; mt < 2; ++mt)
        #pragma unroll
        for (int kk = 0; kk < 2; ++kk) {
            const float* qp = Qg + (w * 32 + mt * 16 + c) * Dh + kk * 32 + quad * 8;
            float4 a = *(const float4*)qp;
            float4 b = *(const float4*)(qp + 4);
            union { short8 s; unsigned u[4]; } uu;
            uu.u[0] = pk_bf16(a.x * qs, a.y * qs);
            uu.u[1] = pk_bf16(a.z * qs, a.w * qs);
            uu.u[2] = pk_bf16(b.x * qs, b.y * qs);
            uu.u[3] = pk_bf16(b.z * qs, b.w * qs);
            qa[mt][kk] = uu.s;
        }
    short8 ones;
    #pragma unroll
    for (int i = 0; i < 8; ++i) ones[i] = (short)0x3F80;
    f32x4 o[2][4];
    #pragma unroll
    for (int mt = 0; mt < 2; ++mt)
        #pragma unroll
        for (int nt = 0; nt < 4; ++nt) o[mt][nt] = (f32x4){0.f, 0.f, 0.f, 0.f};
    f32x4 l_acc[2];
    l_acc[0] = (f32x4){0.f, 0.f, 0.f, 0.f};
    l_acc[1] = (f32x4){0.f, 0.f, 0.f, 0.f};

    for (int kt = 0; kt < S_LEN / 64; ++kt) {
        __syncthreads();
        const float* ktp = Kg + (size_t)kt * 64 * Dh;
        #pragma unroll
        for (int i = 0; i < 2; ++i) {
            const int id = t + i * 256;
            const int key = id >> 3, ch = id & 7;
            const float* kp = ktp + key * Dh + ch * 8;
            float4 a = *(const float4*)kp;
            float4 b = *(const float4*)(kp + 4);
            uint4 u;
            u.x = pk_bf16(a.x, a.y); u.y = pk_bf16(a.z, a.w);
            u.z = pk_bf16(b.x, b.y); u.w = pk_bf16(b.z, b.w);
            *(uint4*)&Ks[key * LDS_LD + ch * 8] = u;
        }
        const float* vtp = Vg + (size_t)kt * 64 * Dh;
        {
            const int p2 = t & 31, dcg = t >> 5;
            const int k0 = 32 * (p2 & 1) + (p2 >> 1);
            #pragma unroll
            for (int rr = 0; rr < 2; ++rr) {
                const int dc = dcg + 8 * rr;
                const float* vp = vtp + (size_t)k0 * Dh + dc * 4;
                float4 v0 = *(const float4*)vp;
                float4 v1 = *(const float4*)(vp + 16 * Dh);
                *(unsigned*)&Vt[(dc * 4 + 0) * LDS_LD + 2 * p2] = pk_bf16(v0.x, v1.x);
                *(unsigned*)&Vt[(dc * 4 + 1) * LDS_LD + 2 * p2] = pk_bf16(v0.y, v1.y);
                *(unsigned*)&Vt[(dc * 4 + 2) * LDS_LD + 2 * p2] = pk_bf16(v0.z, v1.z);
                *(unsigned*)&Vt[(dc * 4 + 3) * LDS_LD + 2 * p2] = pk_bf16(v0.w, v1.w);
            }
        }
        __syncthreads();

        f32x4 s[2][4];
        #pragma unroll
        for (int mt = 0; mt < 2; ++mt)
            #pragma unroll
            for (int nt = 0; nt < 4; ++nt) s[mt][nt] = (f32x4){0.f, 0.f, 0.f, 0.f};
        #pragma unroll
        for (int nt = 0; nt < 4; ++nt)
            #pragma unroll
            for (int kk = 0; kk < 2; ++kk) {
                short8 kf = *(const short8*)&Ks[(c + 16 * nt) * LDS_LD + quad * 8 + 32 * kk];
                s[0][nt] = mfma16(qa[0][kk], kf, s[0][nt]);
                s[1][nt] = mfma16(qa[1][kk], kf, s[1][nt]);
            }
        #pragma unroll
        for (int mt = 0; mt < 2; ++mt)
            #pragma unroll
            for (int r = 0; r < 4; ++r) {
                const float e0 = __builtin_amdgcn_exp2f(s[mt][0][r]);
                const float e1 = __builtin_amdgcn_exp2f(s[mt][1][r]);
                const float e2 = __builtin_amdgcn_exp2f(s[mt][2][r]);
                const float e3 = __builtin_amdgcn_exp2f(s[mt][3][r]);
                const unsigned lo = pk_trunc(e0, e1);
                const unsigned hi = pk_trunc(e2, e3);
                const unsigned plo = dpp_xor1_u(lo);
                const unsigned phi = dpp_xor1_u(hi);
                if (!(c & 1)) {
                    uint4 u; u.x = lo; u.y = hi; u.z = plo; u.w = phi;
                    *(uint4*)&Ps[wPoff + (mt * 16 + quad * 4 + r) * LDS_LD + 4 * c] = u;
                }
            }
        short8 pa[2][2];
        #pragma unroll
        for (int mt = 0; mt < 2; ++mt)
            #pragma unroll
            for (int kk = 0; kk < 2; ++kk)
                pa[mt][kk] = *(const short8*)&Ps[wPoff + (mt * 16 + c) * LDS_LD + kk * 32 + quad * 8];
        #pragma unroll
        for (int mt = 0; mt < 2; ++mt) {
            l_acc[mt] = mfma16(pa[mt][0], ones, l_acc[mt]);
            l_acc[mt] = mfma16(pa[mt][1], ones, l_acc[mt]);
        }
        #pragma unroll
        for (int nt = 0; nt < 4; ++nt)
            #pragma unroll
            for (int kk = 0; kk < 2; ++kk) {
                short8 vf = *(const short8*)&Vt[(c + 16 * nt) * LDS_LD + kk * 32 + quad * 8];
                o[0][nt] = mfma16(pa[0][kk], vf, o[0][nt]);
                o[1][nt] = mfma16(pa[1][kk], vf, o[1][nt]);
            }
    }
    #pragma unroll
    for (int mt = 0; mt < 2; ++mt) {
        float inv[4];
        #pragma unroll
        for (int r = 0; r < 4; ++r) inv[r] = 1.0f / l_acc[mt][r];
        #pragma unroll
        for (int nt = 0; nt < 4; ++nt)
            #pragma unroll
            for (int r = 0; r < 4; ++r)
                Og[(w * 32 + mt * 16 + quad * 4 + r) * Dh + c + 16 * nt] =
                    o[mt][nt][r] * inv[r];
    }
}

extern "C" void kernel_launch(void* const* d_in, const int* in_sizes, int n_in,
                              void* d_out, int out_size, void* d_ws, size_t ws_size,
                              hipStream_t stream) {
    const float* K     = (const float*)d_in[0];
    const float* Q     = (const float*)d_in[1];
    const float* V     = (const float*)d_in[2];
    const float* scale = (const float*)d_in[3];
    float* Out = (float*)d_out;

    const size_t tens = (size_t)64 * S_LEN * Dh;          // elements per tensor
    const size_t need = 2 * tens * sizeof(short);         // 33.55 MB
    if (ws_size >= need) {
        short* Kb  = (short*)d_ws;
        short* VtG = Kb + tens;
        prepass<<<dim3(64 * 32), dim3(256), 0, stream>>>(K, V, Kb, VtG);
        fattn_mfma3<<<dim3(1024), dim3(256), 0, stream>>>(Kb, VtG, Q, scale, Out);
    } else {
        fattn_mfma2<<<dim3(1024), dim3(256), 0, stream>>>(K, Q, V, scale, Out);
    }
}